// Round 1
// 505.175 us; speedup vs baseline: 1.0344x; 1.0344x over previous
//
#include <hip/hip_runtime.h>
#include <hip/hip_bf16.h>

#define B_DIM 4096
#define UNITS_DIM 2048
#define K_DIM 4096   // INP + UNITS concatenated
#define M_DIM 8192   // 4 gates * UNITS, interleaved n = u*4 + g

typedef __bf16 bf16x8 __attribute__((ext_vector_type(8)));
typedef float f32x4 __attribute__((ext_vector_type(4)));

#define AS1C(p) ((const __attribute__((address_space(1))) void*)(p))
#define AS3(p)  ((__attribute__((address_space(3))) void*)(p))

__device__ __forceinline__ float fast_sigmoid(float x) {
    return 1.0f / (1.0f + __expf(-x));
}
__device__ __forceinline__ float fast_tanh(float x) {
    return 2.0f / (1.0f + __expf(-2.0f * x)) - 1.0f;
}

// ---------------------------------------------------------------------------
// Kernel 1: Abf[b][k] = bf16( k<2048 ? x[b][k] : pre_h[b][k-2048] )
// ---------------------------------------------------------------------------
__global__ void convert_act(const float* __restrict__ pre_h,
                            const float* __restrict__ x,
                            __hip_bfloat16* __restrict__ Abf) {
    const long long idx = (long long)blockIdx.x * blockDim.x + threadIdx.x;
    const long long e = idx * 8;
    const int b = (int)(e >> 12);
    const int k = (int)(e & 4095);
    const float* src = (k < UNITS_DIM)
        ? (x + (long long)b * UNITS_DIM + k)
        : (pre_h + (long long)b * UNITS_DIM + (k - UNITS_DIM));
    float4 f0 = ((const float4*)src)[0];
    float4 f1 = ((const float4*)src)[1];
    union { __hip_bfloat16 h[8]; uint4 u4; } p;
    p.h[0] = __float2bfloat16(f0.x); p.h[1] = __float2bfloat16(f0.y);
    p.h[2] = __float2bfloat16(f0.z); p.h[3] = __float2bfloat16(f0.w);
    p.h[4] = __float2bfloat16(f1.x); p.h[5] = __float2bfloat16(f1.y);
    p.h[6] = __float2bfloat16(f1.z); p.h[7] = __float2bfloat16(f1.w);
    *(uint4*)(Abf + e) = p.u4;
}

// ---------------------------------------------------------------------------
// Kernel 2: Bbf[n][k], n = u*4+g:  k<2048 ? W[g][u][k] : U[g][u][k-2048]
// ---------------------------------------------------------------------------
__global__ void convert_wu(const float* __restrict__ W,
                           const float* __restrict__ U,
                           __hip_bfloat16* __restrict__ Bbf) {
    const long long idx = (long long)blockIdx.x * blockDim.x + threadIdx.x;
    const long long e = idx * 8;
    const int n = (int)(e >> 12);
    const int k = (int)(e & 4095);
    const int u = n >> 2;
    const int g = n & 3;
    const float* src = (k < UNITS_DIM)
        ? (W + ((long long)g * UNITS_DIM + u) * UNITS_DIM + k)
        : (U + ((long long)g * UNITS_DIM + u) * UNITS_DIM + (k - UNITS_DIM));
    float4 f0 = ((const float4*)src)[0];
    float4 f1 = ((const float4*)src)[1];
    union { __hip_bfloat16 h[8]; uint4 u4; } p;
    p.h[0] = __float2bfloat16(f0.x); p.h[1] = __float2bfloat16(f0.y);
    p.h[2] = __float2bfloat16(f0.z); p.h[3] = __float2bfloat16(f0.w);
    p.h[4] = __float2bfloat16(f1.x); p.h[5] = __float2bfloat16(f1.y);
    p.h[6] = __float2bfloat16(f1.z); p.h[7] = __float2bfloat16(f1.w);
    *(uint4*)(Bbf + e) = p.u4;
}

// ---------------------------------------------------------------------------
// Kernel 3: 256x256-tile bt-GEMM, 8 waves (2M x 4N, 128x64 per wave), BK=32,
// 4-deep LDS ring with counted vmcnt (never 0 in steady state), one barrier
// per K-step, setprio around the MFMA cluster. Fused LSTM epilogue.
//
// Ring-safety invariants (1 barrier/step):
//  - reads of tile t complete (lgkmcnt(0)) before step t's barrier, so the
//    stage of tile t+4 into the same buffer (issued at step t+1, i.e. after
//    that barrier) cannot race the reads.
//  - vmcnt(8) at step t (after issuing tile t+3) forces tile t+1 landed;
//    the following barrier makes that global before anyone reads it at t+1.
//  - steady state keeps 2 tiles (8 global_load_lds) in flight across the
//    barrier; only the final 3 of 128 steps drain lower.
//
// LDS swizzle (both-sides, global_load_lds-compatible): row r's 4 chunks of
// 8 bf16 are stored permuted by c ^ ((r>>1)&3); within any 8 consecutive
// lanes of a ds_read_b128 the (row-parity, chunk-group) pairs are all
// distinct -> conflict-free.
// ---------------------------------------------------------------------------
__global__ __launch_bounds__(512, 2) void lstm_gemm(
    const __hip_bfloat16* __restrict__ Wc,   // 8192 x 4096 (A operand)
    const __hip_bfloat16* __restrict__ Ac,   // 4096 x 4096 (B operand)
    const float* __restrict__ pre_c,         // 4096 x 2048
    float* __restrict__ out)                 // (2, 4096, 2048)
{
    __shared__ __hip_bfloat16 As[4 * 8192];  // 4 bufs x 256 rows x 32 cols
    __shared__ __hip_bfloat16 Bs[4 * 8192];

    const int tid  = threadIdx.x;
    const int lane = tid & 63;
    const int wave = tid >> 6;

    // XCD-aware bijective swizzle of the 512-block grid (512 % 8 == 0)
    const int bid  = blockIdx.x;
    const int wgid = (bid & 7) * 64 + (bid >> 3);
    const int m_base = (wgid & 31) * 256;
    const int n_base = (wgid >> 5) * 256;

    const int wm  = (wave >> 2) * 128;   // 2 waves in M
    const int wn  = (wave & 3) * 64;     // 4 waves in N
    const int l15 = lane & 15;
    const int lq  = lane >> 4;
    const int keyr = (l15 >> 1) & 3;     // read-side swizzle key ((row>>1)&3)

    // frag LDS element offsets within one buffer (row*32 + swizzled_chunk*8)
    const int aofs = (wm + l15) * 32 + ((lq ^ keyr) * 8);
    const int bofs = (wn + l15) * 32 + ((lq ^ keyr) * 8);

    // staging: thread t -> row r0 = t>>2 (and r0+128), chunk c = t&3.
    // Fetch global chunk c ^ ((r0>>1)&3); LDS dest stays linear (tid*16 B).
    const int r0 = tid >> 2;
    const int gc = (((tid & 3) ^ ((tid >> 3) & 3)) * 8);
    const __hip_bfloat16* wg0 = Wc + (size_t)(m_base + r0) * K_DIM + gc;
    const __hip_bfloat16* ag0 = Ac + (size_t)(n_base + r0) * K_DIM + gc;

#define STAGE(T) do {                                                          \
        const int sb_ = (T) & 3;                                               \
        const size_t ko_ = (size_t)(T) * 32;                                   \
        __builtin_amdgcn_global_load_lds(AS1C(wg0 + ko_),                      \
            AS3(As + sb_ * 8192 + tid * 8), 16, 0, 0);                         \
        __builtin_amdgcn_global_load_lds(AS1C(wg0 + (size_t)128 * K_DIM + ko_),\
            AS3(As + sb_ * 8192 + 4096 + tid * 8), 16, 0, 0);                  \
        __builtin_amdgcn_global_load_lds(AS1C(ag0 + ko_),                      \
            AS3(Bs + sb_ * 8192 + tid * 8), 16, 0, 0);                         \
        __builtin_amdgcn_global_load_lds(AS1C(ag0 + (size_t)128 * K_DIM + ko_),\
            AS3(Bs + sb_ * 8192 + 4096 + tid * 8), 16, 0, 0);                  \
    } while (0)

    f32x4 acc[8][4] = {};

    // prologue: stage tiles 0,1,2 into bufs 0,1,2; force tile 0 landed.
    STAGE(0);
    STAGE(1);
    STAGE(2);
    asm volatile("s_waitcnt vmcnt(8)" ::: "memory");
    __builtin_amdgcn_s_barrier();

    for (int t = 0; t < 128; ++t) {
        const int buf = t & 3;
        const __hip_bfloat16* Ab = As + buf * 8192 + aofs;
        const __hip_bfloat16* Bb = Bs + buf * 8192 + bofs;
        bf16x8 af[8], bfv[4];
#pragma unroll
        for (int mi = 0; mi < 8; ++mi)
            af[mi] = *(const bf16x8*)(Ab + mi * 512);
#pragma unroll
        for (int ni = 0; ni < 4; ++ni)
            bfv[ni] = *(const bf16x8*)(Bb + ni * 512);

        if (t < 125) STAGE(t + 3);

        __builtin_amdgcn_sched_barrier(0);
        asm volatile("s_waitcnt lgkmcnt(0)" ::: "memory");   // frags in regs
        if (t < 125)
            asm volatile("s_waitcnt vmcnt(8)" ::: "memory"); // tile t+1 landed
        else if (t == 125)
            asm volatile("s_waitcnt vmcnt(4)" ::: "memory");
        else
            asm volatile("s_waitcnt vmcnt(0)" ::: "memory");
        __builtin_amdgcn_s_barrier();
        __builtin_amdgcn_sched_barrier(0);

        __builtin_amdgcn_s_setprio(1);
#pragma unroll
        for (int mi = 0; mi < 8; ++mi)
#pragma unroll
            for (int ni = 0; ni < 4; ++ni)
                acc[mi][ni] = __builtin_amdgcn_mfma_f32_16x16x32_bf16(
                    af[mi], bfv[ni], acc[mi][ni], 0, 0, 0);
        __builtin_amdgcn_s_setprio(0);
    }
#undef STAGE

    // Fused LSTM epilogue — each lane's frag = (i,f,o,n~) for one (b,u)
#pragma unroll
    for (int mi = 0; mi < 8; ++mi) {
        const int u = ((m_base + wm + mi * 16) >> 2) + lq;
#pragma unroll
        for (int ni = 0; ni < 4; ++ni) {
            const int b = n_base + wn + ni * 16 + l15;
            f32x4 gv = acc[mi][ni];
            float i_t = fast_sigmoid(gv[0]);
            float f_t = fast_sigmoid(gv[1]);
            float o_t = fast_sigmoid(gv[2]);
            float n_t = fast_tanh(gv[3]);
            float pc  = pre_c[(size_t)b * UNITS_DIM + u];
            float c   = f_t * pc + i_t * n_t;
            float h   = o_t * fast_tanh(c);
            out[(size_t)b * UNITS_DIM + u] = h;
            out[(size_t)B_DIM * UNITS_DIM + (size_t)b * UNITS_DIM + u] = c;
        }
    }
}

extern "C" void kernel_launch(void* const* d_in, const int* in_sizes, int n_in,
                              void* d_out, int out_size, void* d_ws, size_t ws_size,
                              hipStream_t stream) {
    const float* pre_layer = (const float*)d_in[0];   // (2, 4096, 2048)
    const float* x         = (const float*)d_in[1];   // (4096, 2048)
    const float* W         = (const float*)d_in[2];   // (4, 2048, 2048)
    const float* U         = (const float*)d_in[3];   // (4, 2048, 2048)
    float* out = (float*)d_out;

    const float* pre_h = pre_layer;
    const float* pre_c = pre_layer + (size_t)B_DIM * UNITS_DIM;

    __hip_bfloat16* Abf = (__hip_bfloat16*)d_ws;                       // 32 MiB
    __hip_bfloat16* Bbf = (__hip_bfloat16*)((char*)d_ws +
                          (size_t)B_DIM * K_DIM * sizeof(__hip_bfloat16)); // 64 MiB

    convert_act<<<8192, 256, 0, stream>>>(pre_h, x, Abf);
    convert_wu<<<16384, 256, 0, stream>>>(W, U, Bbf);

    lstm_gemm<<<512, 512, 0, stream>>>(Bbf, Abf, pre_c, out);
}